// Round 8
// baseline (8166.270 us; speedup 1.0000x reference)
//
#include <hip/hip_runtime.h>

#define B_ 64
#define T_ 2048
#define F_ 8
#define H_ 128
#define RING_LD 68   // 64 dwords + 4 pad for the OUT burst reads

typedef _Float16 v2h   __attribute__((ext_vector_type(2)));
typedef _Float16 f16x8 __attribute__((ext_vector_type(8)));
typedef float    f32x4 __attribute__((ext_vector_type(4)));

// pack two fp32 into one dword of two f16
__device__ __forceinline__ unsigned pk2h(float lo, float hi) {
    v2h p;
    p[0] = (_Float16)lo;
    p[1] = (_Float16)hi;
    return __builtin_bit_cast(unsigned, p);
}

#if __has_builtin(__builtin_amdgcn_fdot2)
__device__ __forceinline__ float fdot2a(unsigned a, unsigned b, float c) {
    return __builtin_amdgcn_fdot2(__builtin_bit_cast(v2h, a),
                                  __builtin_bit_cast(v2h, b), c, false);
}
#else
__device__ __forceinline__ float fdot2a(unsigned a, unsigned b, float c) {
    v2h av = __builtin_bit_cast(v2h, a);
    v2h bv = __builtin_bit_cast(v2h, b);
    c += (float)av[0] * (float)bv[0];
    c += (float)av[1] * (float)bv[1];
    return c;
}
#endif

__device__ __forceinline__ float sigm(float x) {
    return 1.0f / (1.0f + __expf(-x));
}
__device__ __forceinline__ float tanh_f(float x) {
    float e = __expf(2.0f * x);
    return 1.0f - 2.0f / (e + 1.0f);
}

__device__ __forceinline__ f32x4 mfma16(f16x8 a, f16x8 b, f32x4 c) {
    return __builtin_amdgcn_mfma_f32_16x16x32_f16(a, b, c, 0, 0, 0);
}

// ---------------------------------------------------------------------------
// 256 threads = 4 waves; wave w owns h indices [w*32, w*32+32) as two
// column-groups cg in {0,1}: h = w*32 + cg*16 + n, n = lane&15.
// Register budget: 4 waves/CU -> 1 wave/SIMD -> 512 unified regs/wave.
//   ih1+hh1 B-frags (64 frags = 256 dwords) pinned to AGPR ("+a" empty asm;
//     MFMA reads AGPR B operands natively, no copies),
//   hh0 B-frags (32 frags = 128 dwords) pinned to VGPR,
//   accs/temps ~90 VGPR. Total ~474 <= 512.
// (Rounds 0-7 all ran 8 waves: 8 x 192 weight dwords = 1536 regs = the whole
// CU file with zero slack -> allocator AGPR-homed weights and paid a
// v_accvgpr_read per use, ~500 VALU insts/wave/tick. This config has slack.)
// Fragment math identical to round-7 kernel (harness-verified, absmax 4.9e-4).
// ---------------------------------------------------------------------------
__global__ __launch_bounds__(256, 1)
__attribute__((amdgpu_waves_per_eu(1, 1)))
void lstm2_mfma4_kernel(const float* __restrict__ x,
                        const float* __restrict__ wih0,
                        const float* __restrict__ whh0,
                        const float* __restrict__ bih0,
                        const float* __restrict__ bhh0,
                        const float* __restrict__ wih1,
                        const float* __restrict__ whh1,
                        const float* __restrict__ bih1,
                        const float* __restrict__ bhh1,
                        const float* __restrict__ wlin,
                        const float* __restrict__ blin,
                        float* __restrict__ out)
{
    __shared__ __align__(16) unsigned x_lds[T_ * F_ / 2];     // 32 KB packed f16 x
    __shared__ __align__(16) unsigned h0_lds[2][H_ / 2];      // double-buffered h0 (f16)
    __shared__ __align__(16) unsigned h1_lds[2][H_ / 2];      // double-buffered h1 (f16)
    __shared__ __align__(16) unsigned h1_ring[64 * RING_LD];  // 64-tick h1 ring (17 KB)
    __shared__ __align__(16) unsigned wlin_p[F_ * RING_LD];   // w_lin rows, padded
    __shared__ __align__(16) uint4    wih0_f[32 * 64];        // Wih0 B-frags (32 KB)
    __shared__ float bias_lds[2][4 * H_];                     // fused biases (4 KB)
    __shared__ float blin_f[F_];

    const int tid = threadIdx.x;
    const int b   = blockIdx.x;
    const int w   = tid >> 6;     // wave 0..3
    const int l   = tid & 63;     // lane
    const int n   = l & 15;       // fragment column
    const int grp = l >> 4;       // k-slice group 0..3

    // ---- stage x[b] into LDS as packed f16 pairs ----
    const float4* xp = (const float4*)(x + (size_t)b * T_ * F_);
    #pragma unroll
    for (int i = 0; i < 16; ++i) {
        int idx = tid + i * 256;          // 4096 float4 total
        float4 v = xp[idx];
        x_lds[idx * 2 + 0] = pk2h(v.x, v.y);
        x_lds[idx * 2 + 1] = pk2h(v.z, v.w);
    }

    // ---- Wih0 B-frags -> LDS (K=8 padded to 32; only grp==0 lanes nonzero) ----
    #pragma unroll
    for (int cg = 0; cg < 2; ++cg) {
        #pragma unroll
        for (int j = 0; j < 4; ++j) {
            f16x8 wf = {};
            if (grp == 0) {
                const float* p = wih0 + (size_t)(j * H_ + w * 32 + cg * 16 + n) * F_;
                #pragma unroll
                for (int jj = 0; jj < 8; ++jj) wf[jj] = (_Float16)p[jj];
            }
            wih0_f[((w * 2 + cg) * 4 + j) * 64 + l] = __builtin_bit_cast(uint4, wf);
        }
    }

    // ---- big weight matrices as B-frags in registers ----
    // frag [cg][j][s]: elem jj = W[j*128 + w*32 + cg*16 + n][s*32 + grp*8 + jj]
    f16x8 whh0f[2][4][4], wih1f[2][4][4], whh1f[2][4][4];
    #pragma unroll
    for (int cg = 0; cg < 2; ++cg) {
        #pragma unroll
        for (int j = 0; j < 4; ++j) {
            const int row = j * H_ + w * 32 + cg * 16 + n;
            #pragma unroll
            for (int s = 0; s < 4; ++s) {
                const float* p0 = whh0 + (size_t)row * H_ + s * 32 + grp * 8;
                const float* p1 = wih1 + (size_t)row * H_ + s * 32 + grp * 8;
                const float* p2 = whh1 + (size_t)row * H_ + s * 32 + grp * 8;
                f16x8 f0, f1, f2;
                #pragma unroll
                for (int jj = 0; jj < 8; ++jj) {
                    f0[jj] = (_Float16)p0[jj];
                    f1[jj] = (_Float16)p1[jj];
                    f2[jj] = (_Float16)p2[jj];
                }
                whh0f[cg][j][s] = f0;
                wih1f[cg][j][s] = f1;
                whh1f[cg][j][s] = f2;
            }
        }
    }
    // zero-cost register-home pins: hh0 -> VGPR; ih1/hh1 -> AGPR
    #pragma unroll
    for (int cg = 0; cg < 2; ++cg)
        #pragma unroll
        for (int j = 0; j < 4; ++j)
            #pragma unroll
            for (int s = 0; s < 4; ++s) {
                asm("" : "+v"(whh0f[cg][j][s]));
                asm("" : "+a"(wih1f[cg][j][s]));
                asm("" : "+a"(whh1f[cg][j][s]));
            }

    // fused biases -> LDS
    for (int i = tid; i < 4 * H_; i += 256) {
        bias_lds[0][i] = bih0[i] + bhh0[i];
        bias_lds[1][i] = bih1[i] + bhh1[i];
    }
    // w_lin: [8][128] fp32 -> padded rows of 64 packed pairs
    #pragma unroll
    for (int r = 0; r < 2; ++r) {
        int idx = tid + r * 256;          // 0..511
        float2 v = ((const float2*)wlin)[idx];
        wlin_p[(idx >> 6) * RING_LD + (idx & 63)] = pk2h(v.x, v.y);
    }
    if (tid < F_) blin_f[tid] = blin[tid];
    if (tid < H_ / 2) {
        h0_lds[0][tid] = 0u; h0_lds[1][tid] = 0u;
        h1_lds[0][tid] = 0u; h1_lds[1][tid] = 0u;
    }
    __syncthreads();

    float c0[2] = {0.0f, 0.0f}, c1[2] = {0.0f, 0.0f};
    const f32x4 Z4 = {0.0f, 0.0f, 0.0f, 0.0f};

    for (int t = 0; t < T_; ++t) {
        const int rp = (t + 1) & 1;   // parity holding state(t-1)
        const int wp = t & 1;         // parity receiving state(t)

        // ---------- phase A: layer 0 ----------
        {
            f32x4 acc[2][4];
            {   // s = 0 (C = 0)
                uint4 hv = *(const uint4*)&h0_lds[rp][grp * 4];
                f16x8 ah = __builtin_bit_cast(f16x8, hv);
                #pragma unroll
                for (int cg = 0; cg < 2; ++cg)
                    #pragma unroll
                    for (int j = 0; j < 4; ++j)
                        acc[cg][j] = mfma16(ah, whh0f[cg][j][0], Z4);
            }
            #pragma unroll
            for (int s = 1; s < 4; ++s) {
                uint4 hv = *(const uint4*)&h0_lds[rp][s * 16 + grp * 4];
                f16x8 ah = __builtin_bit_cast(f16x8, hv);
                #pragma unroll
                for (int cg = 0; cg < 2; ++cg)
                    #pragma unroll
                    for (int j = 0; j < 4; ++j)
                        acc[cg][j] = mfma16(ah, whh0f[cg][j][s], acc[cg][j]);
            }
            {   // x contribution last (B fresh from LDS -> VGPR; compiler-managed)
                uint4 xv = *(const uint4*)&x_lds[t * 4];
                f16x8 ax = __builtin_bit_cast(f16x8, xv);
                if (grp != 0) ax = (f16x8){};
                #pragma unroll
                for (int cg = 0; cg < 2; ++cg)
                    #pragma unroll
                    for (int j = 0; j < 4; ++j)
                        acc[cg][j] = mfma16(
                            ax,
                            __builtin_bit_cast(f16x8, wih0_f[((w * 2 + cg) * 4 + j) * 64 + l]),
                            acc[cg][j]);
            }
            #pragma unroll
            for (int cg = 0; cg < 2; ++cg) {
                const int hrow = w * 32 + cg * 16 + n;
                float gi = sigm(acc[cg][0][0] + bias_lds[0][0 * H_ + hrow]);
                float gf = sigm(acc[cg][1][0] + bias_lds[0][1 * H_ + hrow]);
                float gg = tanh_f(acc[cg][2][0] + bias_lds[0][2 * H_ + hrow]);
                float go = sigm(acc[cg][3][0] + bias_lds[0][3 * H_ + hrow]);
                c0[cg] = gf * c0[cg] + gi * gg;
                float hh = go * tanh_f(c0[cg]);
                if (l < 16) ((_Float16*)&h0_lds[wp][0])[w * 32 + cg * 16 + l] = (_Float16)hh;
            }
        }

        __syncthreads();   // h0(t) visible

        // ---------- phase B: layer 1 ----------
        {
            f32x4 acc[2][4];
            {   // ih1, s = 0 (C = 0), A = h0(t)
                uint4 hv = *(const uint4*)&h0_lds[wp][grp * 4];
                f16x8 ah = __builtin_bit_cast(f16x8, hv);
                #pragma unroll
                for (int cg = 0; cg < 2; ++cg)
                    #pragma unroll
                    for (int j = 0; j < 4; ++j)
                        acc[cg][j] = mfma16(ah, wih1f[cg][j][0], Z4);
            }
            #pragma unroll
            for (int s = 1; s < 4; ++s) {
                uint4 hv = *(const uint4*)&h0_lds[wp][s * 16 + grp * 4];
                f16x8 ah = __builtin_bit_cast(f16x8, hv);
                #pragma unroll
                for (int cg = 0; cg < 2; ++cg)
                    #pragma unroll
                    for (int j = 0; j < 4; ++j)
                        acc[cg][j] = mfma16(ah, wih1f[cg][j][s], acc[cg][j]);
            }
            #pragma unroll
            for (int s = 0; s < 4; ++s) {   // hh1, A = h1(t-1)
                uint4 hv = *(const uint4*)&h1_lds[rp][s * 16 + grp * 4];
                f16x8 ah = __builtin_bit_cast(f16x8, hv);
                #pragma unroll
                for (int cg = 0; cg < 2; ++cg)
                    #pragma unroll
                    for (int j = 0; j < 4; ++j)
                        acc[cg][j] = mfma16(ah, whh1f[cg][j][s], acc[cg][j]);
            }
            #pragma unroll
            for (int cg = 0; cg < 2; ++cg) {
                const int hrow = w * 32 + cg * 16 + n;
                float gi = sigm(acc[cg][0][0] + bias_lds[1][0 * H_ + hrow]);
                float gf = sigm(acc[cg][1][0] + bias_lds[1][1 * H_ + hrow]);
                float gg = tanh_f(acc[cg][2][0] + bias_lds[1][2 * H_ + hrow]);
                float go = sigm(acc[cg][3][0] + bias_lds[1][3 * H_ + hrow]);
                c1[cg] = gf * c1[cg] + gi * gg;
                float hh = go * tanh_f(c1[cg]);
                if (l < 16) {
                    _Float16 hf = (_Float16)hh;
                    ((_Float16*)&h1_lds[wp][0])[w * 32 + cg * 16 + l] = hf;
                    ((_Float16*)h1_ring)[(t & 63) * (RING_LD * 2) + w * 32 + cg * 16 + l] = hf;
                }
            }
        }

        __syncthreads();   // h1(t) + ring slot visible

        // ---------- OUT burst: every 64 ticks, 512 outputs (2 per thread) ----------
        if ((t & 63) == 63) {
            #pragma unroll
            for (int r = 0; r < 2; ++r) {
                const int idx    = tid + r * 256;
                const int tick_i = idx >> 3;   // ring slot == tick (t-63+tick_i)
                const int fo     = idx & 7;    // output feature
                const unsigned* hp = &h1_ring[tick_i * RING_LD];
                const unsigned* wv = &wlin_p[fo * RING_LD];
                float a = 0.0f;
                #pragma unroll
                for (int j = 0; j < 16; ++j) {
                    uint4 hv = *(const uint4*)&hp[j * 4];
                    uint4 wq = *(const uint4*)&wv[j * 4];
                    a = fdot2a(wq.x, hv.x, a);
                    a = fdot2a(wq.y, hv.y, a);
                    a = fdot2a(wq.z, hv.z, a);
                    a = fdot2a(wq.w, hv.w, a);
                }
                out[(size_t)b * T_ * F_ + (size_t)(t - 63) * F_ + idx] = a + blin_f[fo];
            }
            // stores drain at the next phase-A barrier (once per 64 ticks)
        }
    }
}

extern "C" void kernel_launch(void* const* d_in, const int* in_sizes, int n_in,
                              void* d_out, int out_size, void* d_ws, size_t ws_size,
                              hipStream_t stream) {
    const float* x    = (const float*)d_in[0];
    const float* wih0 = (const float*)d_in[1];
    const float* whh0 = (const float*)d_in[2];
    const float* bih0 = (const float*)d_in[3];
    const float* bhh0 = (const float*)d_in[4];
    const float* wih1 = (const float*)d_in[5];
    const float* whh1 = (const float*)d_in[6];
    const float* bih1 = (const float*)d_in[7];
    const float* bhh1 = (const float*)d_in[8];
    const float* wlin = (const float*)d_in[9];
    const float* blin = (const float*)d_in[10];
    float* out = (float*)d_out;

    lstm2_mfma4_kernel<<<dim3(B_), dim3(256), 0, stream>>>(
        x, wih0, whh0, bih0, bhh0, wih1, whh1, bih1, bhh1, wlin, blin, out);
}

// Round 10
// 3530.334 us; speedup vs baseline: 2.3132x; 2.3132x over previous
//
#include <hip/hip_runtime.h>

#define B_ 64
#define T_ 2048
#define F_ 8
#define H_ 128
#define RING_LD 68     // 64 dwords + 4 pad per ring slot
#define RING_N  128    // 128-slot h1 ring (window 64 + in-flight slack)

typedef _Float16 v2h   __attribute__((ext_vector_type(2)));
typedef _Float16 f16x8 __attribute__((ext_vector_type(8)));
typedef float    f32x4 __attribute__((ext_vector_type(4)));

__device__ __forceinline__ unsigned pk2h(float lo, float hi) {
    v2h p;
    p[0] = (_Float16)lo;
    p[1] = (_Float16)hi;
    return __builtin_bit_cast(unsigned, p);
}

#if __has_builtin(__builtin_amdgcn_fdot2)
__device__ __forceinline__ float fdot2a(unsigned a, unsigned b, float c) {
    return __builtin_amdgcn_fdot2(__builtin_bit_cast(v2h, a),
                                  __builtin_bit_cast(v2h, b), c, false);
}
#else
__device__ __forceinline__ float fdot2a(unsigned a, unsigned b, float c) {
    v2h av = __builtin_bit_cast(v2h, a);
    v2h bv = __builtin_bit_cast(v2h, b);
    c += (float)av[0] * (float)bv[0];
    c += (float)av[1] * (float)bv[1];
    return c;
}
#endif

__device__ __forceinline__ float sigm(float x) {
    return 1.0f / (1.0f + __expf(-x));
}
__device__ __forceinline__ float tanh_f(float x) {
    float e = __expf(2.0f * x);
    return 1.0f - 2.0f / (e + 1.0f);
}

__device__ __forceinline__ f32x4 mfma16(f16x8 a, f16x8 b, f32x4 c) {
    return __builtin_amdgcn_mfma_f32_16x16x32_f16(a, b, c, 0, 0, 0);
}

// ---------------------------------------------------------------------------
// 512 threads = 8 waves; wave w owns h indices [w*16, w*16+16), n = lane&15.
// MFMA formulation identical to the harness-verified round-7 kernel:
//   A[m][k] = h[k] broadcast (D row-replicated), B[k][n] = W[j*128+w*16+n][k],
//   same k-enumeration (grp=l>>4, elem jj -> k = s*32+grp*8+jj) on both sides.
// Structure (round-9 hypothesis, bugs fixed):
//  1. SOFTWARE-PIPELINED TICK: one region computes L0(t) || L1(t-1) — two
//     independent MFMA chains the scheduler interleaves — then ONE barrier.
//  2. Register homes explicit: ih1+hh1 B-frags "+a" = 128 AGPRs (MFMA reads
//     AGPR B natively, r8-proven); whh0 "+v"; total ~250 of the 256/wave cap.
//     __launch_bounds__(512,2): 8-wave block NEEDS <=256 regs/wave to launch
//     (r9's (512,1) allowed >256 -> unlaunchable -> abort).
//  3. h1 history in a 128-slot LDS ring; verified 64-tick OUT burst at
//     t%64==1 covering ticks t-65..t-2. r9 bug fixed: store index is
//     base + (t-65)*F + tid (tid already enumerates tick x feature; the
//     tl*F+tid form double-counted and ran OOB -> memory fault).
// ---------------------------------------------------------------------------
__global__ __launch_bounds__(512, 2)
void lstm2_pipe_mfma_kernel(const float* __restrict__ x,
                            const float* __restrict__ wih0,
                            const float* __restrict__ whh0,
                            const float* __restrict__ bih0,
                            const float* __restrict__ bhh0,
                            const float* __restrict__ wih1,
                            const float* __restrict__ whh1,
                            const float* __restrict__ bih1,
                            const float* __restrict__ bhh1,
                            const float* __restrict__ wlin,
                            const float* __restrict__ blin,
                            float* __restrict__ out)
{
    __shared__ __align__(16) unsigned x_lds[T_ * F_ / 2];        // 32 KB packed f16 x
    __shared__ __align__(16) unsigned h0_lds[2][H_ / 2];         // double-buffered h0
    __shared__ __align__(16) unsigned h1_ring[RING_N * RING_LD]; // 34.8 KB h1 ring
    __shared__ __align__(16) unsigned wlin_p[F_ * RING_LD];      // w_lin rows, padded
    __shared__ __align__(16) uint4    wih0_f[8 * 4 * 64];        // Wih0 B-frags (32 KB)
    __shared__ float blin_f[F_];

    const int tid = threadIdx.x;
    const int b   = blockIdx.x;
    const int w   = tid >> 6;     // wave 0..7
    const int l   = tid & 63;     // lane
    const int n   = l & 15;       // fragment column == h offset
    const int grp = l >> 4;       // k-slice group 0..3

    // ---- stage x[b] into LDS as packed f16 pairs ----
    const float4* xp = (const float4*)(x + (size_t)b * T_ * F_);
    #pragma unroll
    for (int i = 0; i < 8; ++i) {
        int idx = tid + i * 512;
        float4 v = xp[idx];
        x_lds[idx * 2 + 0] = pk2h(v.x, v.y);
        x_lds[idx * 2 + 1] = pk2h(v.z, v.w);
    }

    // ---- Wih0 B-frags -> LDS (K=8 padded to 32; only grp==0 lanes nonzero) ----
    #pragma unroll
    for (int j = 0; j < 4; ++j) {
        f16x8 wf = {};
        if (grp == 0) {
            const float* p = wih0 + (size_t)(j * H_ + w * 16 + n) * F_;
            #pragma unroll
            for (int jj = 0; jj < 8; ++jj) wf[jj] = (_Float16)p[jj];
        }
        wih0_f[(w * 4 + j) * 64 + l] = __builtin_bit_cast(uint4, wf);
    }

    // ---- big weight matrices as B-frags; explicit register homes ----
    // frag [j][s]: elem jj = W[j*128 + w*16 + n][s*32 + grp*8 + jj]
    f16x8 whh0f[4][4], wih1f[4][4], whh1f[4][4];
    #pragma unroll
    for (int j = 0; j < 4; ++j) {
        const int row = j * H_ + w * 16 + n;
        #pragma unroll
        for (int s = 0; s < 4; ++s) {
            const float* p0 = whh0 + (size_t)row * H_ + s * 32 + grp * 8;
            const float* p1 = wih1 + (size_t)row * H_ + s * 32 + grp * 8;
            const float* p2 = whh1 + (size_t)row * H_ + s * 32 + grp * 8;
            f16x8 f0, f1, f2;
            #pragma unroll
            for (int jj = 0; jj < 8; ++jj) {
                f0[jj] = (_Float16)p0[jj];
                f1[jj] = (_Float16)p1[jj];
                f2[jj] = (_Float16)p2[jj];
            }
            whh0f[j][s] = f0;
            wih1f[j][s] = f1;
            whh1f[j][s] = f2;
        }
    }
    #pragma unroll
    for (int j = 0; j < 4; ++j)
        #pragma unroll
        for (int s = 0; s < 4; ++s) {
            asm("" : "+v"(whh0f[j][s]));   //  64 dw arch VGPR
            asm("" : "+a"(wih1f[j][s]));   // 128 dw AGPR total (a-file)
            asm("" : "+a"(whh1f[j][s]));
        }

    // biases for this lane's 4 gates (8 regs)
    float bb0[4], bb1[4];
    #pragma unroll
    for (int j = 0; j < 4; ++j) {
        const int row = j * H_ + w * 16 + n;
        bb0[j] = bih0[row] + bhh0[row];
        bb1[j] = bih1[row] + bhh1[row];
    }

    // w_lin -> padded LDS rows (OUT burst)
    {
        float2 v = ((const float2*)wlin)[tid];
        wlin_p[(tid >> 6) * RING_LD + (tid & 63)] = pk2h(v.x, v.y);
    }
    if (tid < F_) blin_f[tid] = blin[tid];
    if (tid < H_ / 2) {
        h0_lds[0][tid] = 0u; h0_lds[1][tid] = 0u;
        h1_ring[(RING_N - 1) * RING_LD + tid] = 0u;   // h1(-1) = 0 (slot 127)
    }
    __syncthreads();

    float c0 = 0.0f, c1 = 0.0f;
    const f32x4 Z4 = {0.0f, 0.0f, 0.0f, 0.0f};

    // Iteration t: L0(t) [t < T_]  ||  L1(t-1) [1 <= t <= T_]; one barrier.
    // OUT burst at t%64==1 (t>=65) covers ticks t-65..t-2.
    for (int t = 0; t <= T_ + 1; ++t) {
        const int rp = (t + 1) & 1;   // parity holding h0(t-1)
        const int wp = t & 1;         // parity receiving h0(t)

        // ---------- OUT burst (reads only barrier-protected ring slots) ----------
        if (t >= 65 && (t & 63) == 1) {
            const int tick_i = tid >> 3;           // 0..63
            const int fo     = tid & 7;
            const unsigned* hp = &h1_ring[((t - 65 + tick_i) & (RING_N - 1)) * RING_LD];
            const unsigned* wv = &wlin_p[fo * RING_LD];
            float a = 0.0f;
            #pragma unroll
            for (int j = 0; j < 16; ++j) {
                uint4 hv = *(const uint4*)&hp[j * 4];
                uint4 wq = *(const uint4*)&wv[j * 4];
                a = fdot2a(wq.x, hv.x, a);
                a = fdot2a(wq.y, hv.y, a);
                a = fdot2a(wq.z, hv.z, a);
                a = fdot2a(wq.w, hv.w, a);
            }
            // tid enumerates tick x feature: 512 consecutive floats from (t-65)*F
            out[(size_t)b * T_ * F_ + (size_t)(t - 65) * F_ + tid] = a + blin_f[fo];
            // store drains at this iteration's barrier (32x per sequence)
        }

        // ---------- L0(t): gates0 = Whh0*h0(t-1) + Wih0*x(t) ----------
        if (t < T_) {
            f32x4 acc[4];
            {
                uint4 hv = *(const uint4*)&h0_lds[rp][grp * 4];
                f16x8 ah = __builtin_bit_cast(f16x8, hv);
                #pragma unroll
                for (int j = 0; j < 4; ++j) acc[j] = mfma16(ah, whh0f[j][0], Z4);
            }
            #pragma unroll
            for (int s = 1; s < 4; ++s) {
                uint4 hv = *(const uint4*)&h0_lds[rp][s * 16 + grp * 4];
                f16x8 ah = __builtin_bit_cast(f16x8, hv);
                #pragma unroll
                for (int j = 0; j < 4; ++j) acc[j] = mfma16(ah, whh0f[j][s], acc[j]);
            }
            {
                uint4 xv = *(const uint4*)&x_lds[t * 4];
                f16x8 ax = __builtin_bit_cast(f16x8, xv);
                if (grp != 0) ax = (f16x8){};
                #pragma unroll
                for (int j = 0; j < 4; ++j)
                    acc[j] = mfma16(
                        ax, __builtin_bit_cast(f16x8, wih0_f[(w * 4 + j) * 64 + l]),
                        acc[j]);
            }
            float gi = sigm(acc[0][0] + bb0[0]);
            float gf = sigm(acc[1][0] + bb0[1]);
            float gg = tanh_f(acc[2][0] + bb0[2]);
            float go = sigm(acc[3][0] + bb0[3]);
            c0 = gf * c0 + gi * gg;
            float hh = go * tanh_f(c0);
            if (l < 16) ((_Float16*)&h0_lds[wp][0])[w * 16 + l] = (_Float16)hh;
        }

        // ---------- L1(t-1): gates1 = Wih1*h0(t-1) + Whh1*h1(t-2) ----------
        if (t >= 1 && t <= T_) {
            const unsigned* h1prev = &h1_ring[((t - 2) & (RING_N - 1)) * RING_LD];
            f32x4 acc[4];
            {
                uint4 hv = *(const uint4*)&h0_lds[rp][grp * 4];   // h0(t-1)
                f16x8 ah = __builtin_bit_cast(f16x8, hv);
                #pragma unroll
                for (int j = 0; j < 4; ++j) acc[j] = mfma16(ah, wih1f[j][0], Z4);
            }
            #pragma unroll
            for (int s = 1; s < 4; ++s) {
                uint4 hv = *(const uint4*)&h0_lds[rp][s * 16 + grp * 4];
                f16x8 ah = __builtin_bit_cast(f16x8, hv);
                #pragma unroll
                for (int j = 0; j < 4; ++j) acc[j] = mfma16(ah, wih1f[j][s], acc[j]);
            }
            #pragma unroll
            for (int s = 0; s < 4; ++s) {
                uint4 hv = *(const uint4*)&h1prev[s * 16 + grp * 4];  // h1(t-2)
                f16x8 ah = __builtin_bit_cast(f16x8, hv);
                #pragma unroll
                for (int j = 0; j < 4; ++j) acc[j] = mfma16(ah, whh1f[j][s], acc[j]);
            }
            float gi = sigm(acc[0][0] + bb1[0]);
            float gf = sigm(acc[1][0] + bb1[1]);
            float gg = tanh_f(acc[2][0] + bb1[2]);
            float go = sigm(acc[3][0] + bb1[3]);
            c1 = gf * c1 + gi * gg;
            float hh = go * tanh_f(c1);
            if (l < 16)
                ((_Float16*)&h1_ring[((t - 1) & (RING_N - 1)) * RING_LD])[w * 16 + l] =
                    (_Float16)hh;   // h1(t-1)
        }

        __syncthreads();   // h0(t), h1(t-1) visible; single fence per tick
    }
}

extern "C" void kernel_launch(void* const* d_in, const int* in_sizes, int n_in,
                              void* d_out, int out_size, void* d_ws, size_t ws_size,
                              hipStream_t stream) {
    const float* x    = (const float*)d_in[0];
    const float* wih0 = (const float*)d_in[1];
    const float* whh0 = (const float*)d_in[2];
    const float* bih0 = (const float*)d_in[3];
    const float* bhh0 = (const float*)d_in[4];
    const float* wih1 = (const float*)d_in[5];
    const float* whh1 = (const float*)d_in[6];
    const float* bih1 = (const float*)d_in[7];
    const float* bhh1 = (const float*)d_in[8];
    const float* wlin = (const float*)d_in[9];
    const float* blin = (const float*)d_in[10];
    float* out = (float*)d_out;

    lstm2_pipe_mfma_kernel<<<dim3(B_), dim3(512), 0, stream>>>(
        x, wih0, whh0, bih0, bhh0, wih1, whh1, bih1, bhh1, wlin, blin, out);
}